// Round 10
// baseline (365.606 us; speedup 1.0000x reference)
//
#include <hip/hip_runtime.h>

typedef unsigned short u16;
typedef unsigned int u32;
typedef short short8 __attribute__((ext_vector_type(8)));
typedef float f32x4 __attribute__((ext_vector_type(4)));
typedef float f32x16 __attribute__((ext_vector_type(16)));

#define B_ 4
#define N_ 2048
#define D_ 256
#define H_ 4
#define DH_ 64
#define BN_ 8192

__device__ inline float b2f(u16 u) {
    union { u32 i; float f; } v; v.i = ((u32)u) << 16; return v.f;
}
// round-half-up bf16: 2 VALU ops
__device__ inline u16 f2b(float f) {
    union { float f; u32 i; } v; v.f = f;
    return (u16)((v.i + 0x8000u) >> 16);
}
// pack two f32 -> bf16 pair (lo=a, hi=b) in 3 VALU via v_perm_b32
__device__ inline u32 pkbf(float a, float b) {
    union { float f; u32 i; } ua, ub; ua.f = a; ub.f = b;
    return __builtin_amdgcn_perm(ub.i + 0x8000u, ua.i + 0x8000u, 0x07060302u);
}
__device__ inline f32x4 mfma16(short8 a, short8 b, f32x4 c) {
    return __builtin_amdgcn_mfma_f32_16x16x32_bf16(a, b, c, 0, 0, 0);
}
__device__ inline f32x16 mfma32(short8 a, short8 b, f32x16 c) {
    return __builtin_amdgcn_mfma_f32_32x32x16_bf16(a, b, c, 0, 0, 0);
}

#define QSCALE 0.18033688f   // 0.125 * log2(e)

// -------- weight transpose only (norm moved into gemm_front) ----------------
__global__ __launch_bounds__(256) void transw_k(
    const float* __restrict__ wqkv, const float* __restrict__ wout,
    const float* __restrict__ wgate,
    u16* __restrict__ wqkvT, u16* __restrict__ woutT, u16* __restrict__ wgateT)
{
    int idx = blockIdx.x * 256 + threadIdx.x;   // [0, 262144)
    if (idx < 768 * 256) {
        int nn = idx >> 8, kk = idx & 255;
        wqkvT[idx] = f2b(wqkv[kk * 768 + nn]);
    }
    idx -= 768 * 256;
    if (idx >= 0 && idx < 256 * 256) {
        int nn = idx >> 8, kk = idx & 255;
        woutT[idx]  = f2b(wout[kk * 256 + nn]);
        wgateT[idx] = f2b(wgate[kk * 256 + nn]);
    }
}

// -------- fused norm + front-end GEMM: C = zcrms(x) @ [wqkv | wgate] --------
// Round-10: norm pass + h round-trip removed. Phase 0: each block normalizes
// its own 128 x-rows into LDS As[128][264] (pad-264 -> minimum-conflict MFMA
// A reads; 8x redundant across by, L3-absorbed). K-loop reads A from LDS.
// Epilogue column ranges: [0,512) Q,K with in-register RoPE (pair =
// __shfl_xor(v,1)), [512,768) V transposed into VT, [768,1024) sigmoid gate.
__global__ __launch_bounds__(256) void gemm_front(
    const float* __restrict__ x, const float* __restrict__ gw,
    const u16* __restrict__ BT,                 // [1024][256] = [wqkvT|wgateT]
    const float* __restrict__ b_qkv, const float* __restrict__ b_gate,
    const float* __restrict__ freqs,
    u16* __restrict__ Qb, u16* __restrict__ Kb,
    u16* __restrict__ VT, u16* __restrict__ gatb)
{
    __shared__ __align__(16) u16 As[128][264];
    const int tid = threadIdx.x;
    const int wave = tid >> 6, lane = tid & 63;
    const int ln15 = lane & 15, quad = lane >> 4;
    const int by = blockIdx.y;
    const int mb = blockIdx.x * 128;

    // ---- phase 0: zc-RMSNorm rows mb..mb+127 -> As (each wave: 32 rows)
    {
        const float4 gv = *(const float4*)(gw + lane * 4);
        #pragma unroll 4
        for (int rr = 0; rr < 32; ++rr) {
            const int r = wave * 32 + rr;
            const float4 u = *(const float4*)(x + (size_t)(mb + r) * D_ + lane * 4);
            float s  = u.x + u.y + u.z + u.w;
            float s2 = u.x * u.x + u.y * u.y + u.z * u.z + u.w * u.w;
            #pragma unroll
            for (int m = 1; m < 64; m <<= 1) {
                s  += __shfl_xor(s, m);
                s2 += __shfl_xor(s2, m);
            }
            const float mean = s * (1.0f / D_);
            const float var  = s2 * (1.0f / D_) - mean * mean;
            const float rinv = rsqrtf(var + 1e-8f);
            uint2 o;
            o.x = pkbf((u.x - mean) * rinv * gv.x, (u.y - mean) * rinv * gv.y);
            o.y = pkbf((u.z - mean) * rinv * gv.z, (u.w - mean) * rinv * gv.w);
            *(uint2*)&As[r][lane * 4] = o;
        }
    }
    __syncthreads();

    const int ml0 = (wave & 1) * 64;            // m-local base for this wave
    const int m0  = mb + ml0;                   // global m base
    const int n0  = by * 128 + (wave >> 1) * 64;

    const f32x4 zero = {0.f, 0.f, 0.f, 0.f};
    f32x4 acc[4][4];
    #pragma unroll
    for (int i = 0; i < 4; ++i)
        #pragma unroll
        for (int j = 0; j < 4; ++j) acc[i][j] = zero;

    #pragma unroll
    for (int k0 = 0; k0 < 256; k0 += 32) {
        const int koff = k0 + quad * 8;
        short8 a[4], b[4];
        #pragma unroll
        for (int i = 0; i < 4; ++i)
            a[i] = *(const short8*)&As[ml0 + i * 16 + ln15][koff];
        #pragma unroll
        for (int j = 0; j < 4; ++j)
            b[j] = *(const short8*)(BT + (size_t)(n0 + j * 16 + ln15) * 256 + koff);
        #pragma unroll
        for (int i = 0; i < 4; ++i)
            #pragma unroll
            for (int j = 0; j < 4; ++j)
                acc[i][j] = mfma16(a[i], b[j], acc[i][j]);
    }

    if (by < 4) {
        // ---- Q,K + RoPE. c<256 -> Q (scaled); else K. Pair = lane^1.
        #pragma unroll
        for (int j = 0; j < 4; ++j) {
            const int c  = n0 + j * 16 + ln15;
            const int hh = (c >> 6) & 3;
            const int dh = c & 63;
            const int d2 = dh >> 1;
            const bool isQ = (c < 256);
            const bool ev  = ((dh & 1) == 0);
            const float bv = b_qkv[c];
            u16* dst = isQ ? Qb : Kb;
            #pragma unroll
            for (int i = 0; i < 4; ++i) {
                const int r = m0 + i * 16 + quad * 4;
                #pragma unroll
                for (int rg = 0; rg < 4; ++rg) {
                    const int t = r + rg;
                    const int n = t & 2047, b = t >> 11;
                    float v = acc[i][j][rg] + bv;
                    float pv = __shfl_xor(v, 1);
                    const float2 cs = *(const float2*)(freqs + (size_t)n * 64 + d2 * 2);
                    float o = ev ? (v * cs.x - pv * cs.y)
                                 : (pv * cs.y + v * cs.x);
                    if (isQ) o *= QSCALE;
                    dst[((size_t)(b * H_ + hh) * N_ + n) * DH_ + dh] = f2b(o);
                }
            }
        }
    } else if (by < 6) {
        // ---- V, written directly transposed: VT[bh][dh][n] (8B per store)
        #pragma unroll
        for (int j = 0; j < 4; ++j) {
            const int c  = n0 + j * 16 + ln15;      // 512..767
            const int hh = (c >> 6) & 3;
            const int dh = c & 63;
            const float bv = b_qkv[c];
            #pragma unroll
            for (int i = 0; i < 4; ++i) {
                const int r = m0 + i * 16 + quad * 4;  // r%4==0, same b for rg 0..3
                const int n = r & 2047, b = r >> 11;
                uint2 w;
                w.x = pkbf(acc[i][j][0] + bv, acc[i][j][1] + bv);
                w.y = pkbf(acc[i][j][2] + bv, acc[i][j][3] + bv);
                *(uint2*)(VT + ((size_t)(b * H_ + hh) * DH_ + dh) * N_ + n) = w;
            }
        }
    } else {
        // ---- gate: sigmoid -> gatb[t][256]
        #pragma unroll
        for (int j = 0; j < 4; ++j) {
            const int c  = n0 + j * 16 + ln15;      // 768..1023
            const int cg = c - 768;
            const float bv = b_gate[cg];
            #pragma unroll
            for (int i = 0; i < 4; ++i) {
                const int r = m0 + i * 16 + quad * 4;
                #pragma unroll
                for (int rg = 0; rg < 4; ++rg) {
                    float v = acc[i][j][rg] + bv;
                    gatb[(size_t)(r + rg) * 256 + cg] = f2b(1.0f / (1.0f + __expf(-v)));
                }
            }
        }
    }
}

// -------- flash attention, split-K x8, 32x32 MFMA, in-register softmax ------
// Round-10: occupancy is the only lever that has ever moved this kernel
// (R3->R4, R6->R7: both -13-15% from doubling TLP). 16 -> 32 waves/CU:
// grid 2048 (split-K x8, 256 keys/block) x 8 blocks/CU, LDS 19.5 KB via
// 32-key tiles. Padding (Ks[..][72], Vs[..][40]) gives minimum-conflict
// reads AND writes (row strides 36/20 words: 8-row groups tile all 32
// banks). VGPR cap 64 via __launch_bounds__(256,8) — R9 compiled to exactly
// 64 with more staging state, so this should fit without spill.
__global__ __launch_bounds__(256, 8) void attn_k(
    const u16* __restrict__ Q, const u16* __restrict__ K,
    const u16* __restrict__ VT, u16* __restrict__ Opb,
    float* __restrict__ lvp)
{
    __shared__ __align__(16) u16 Ks[2][32][72];   // 32 keys x 64 dh (pad 72)
    __shared__ __align__(16) u16 Vs[2][64][40];   // 64 dh x 32 keys (pad 40)
    const int tid = threadIdx.x;
    const int wave = tid >> 6, lane = tid & 63;
    const int l31 = lane & 31, hi = lane >> 5;
    const int id = blockIdx.x;
    // XCD swizzle: id&7 -> fixed bh pair per XCD
    const int bh  = ((id & 7) << 1) | ((id >> 3) & 1);
    const int oct = (id >> 4) & 7;
    const int q0  = (id >> 7) * 128 + wave * 32;
    const int kt0 = oct * 256;

    const u16* Qh = Q + (size_t)bh * N_ * DH_;
    const u16* Kh = K + (size_t)bh * N_ * DH_;
    const u16* Vh = VT + (size_t)bh * DH_ * N_;

    // Q as B-operand: col q = l31, k = kc*16 + hi*8 + j
    short8 bq[4];
    #pragma unroll
    for (int kc = 0; kc < 4; ++kc)
        bq[kc] = *(const short8*)(Qh + (size_t)(q0 + l31) * DH_ + kc * 16 + hi * 8);

    f32x16 o0, o1;   // O^T[dh 0..31][q], O^T[dh 32..63][q]
    #pragma unroll
    for (int i = 0; i < 16; ++i) { o0[i] = 0.f; o1[i] = 0.f; }
    float lv = 0.f;

    // staging: K 32x64 (1 uint4/thread), V 64x32 (1 uint4/thread)
    const int srK = tid >> 3, scK = (tid & 7) * 8;
    const int srV = tid >> 2, scV = (tid & 3) * 8;

    {
        uint4 kld = *(const uint4*)(Kh + (size_t)(kt0 + srK) * DH_ + scK);
        uint4 vld = *(const uint4*)(Vh + (size_t)srV * N_ + kt0 + scV);
        *(uint4*)&Ks[0][srK][scK] = kld;
        *(uint4*)&Vs[0][srV][scV] = vld;
    }
    __syncthreads();

    int p = 0;
    for (int c = 0; c < 8; ++c) {
        const bool more = (c + 1 < 8);
        uint4 kld, vld;
        if (more) {
            const int kb = kt0 + (c + 1) * 32;
            kld = *(const uint4*)(Kh + (size_t)(kb + srK) * DH_ + scK);
            vld = *(const uint4*)(Vh + (size_t)srV * N_ + kb + scV);
        }

        // QK^T: S^T[key][q]; A = K rows (key = l31), B = Q
        f32x16 st;
        #pragma unroll
        for (int i = 0; i < 16; ++i) st[i] = 0.f;
        #pragma unroll
        for (int kc = 0; kc < 4; ++kc) {
            short8 ka = *(const short8*)&Ks[p][l31][kc * 16 + hi * 8];
            st = mfma32(ka, bq[kc], st);
        }
        // softmax numerator in place (no running max; QSCALE pre-applied)
        #pragma unroll
        for (int r = 0; r < 16; ++r) {
            st[r] = exp2f(st[r]);
            lv += st[r];
        }
        // pack P into PV B-fragments (T12: cvt_pk + permlane32_swap)
        #pragma unroll
        for (int kc2 = 0; kc2 < 2; ++kc2) {
            u32 X0, X1, Y0, Y1;
            asm("v_cvt_pk_bf16_f32 %0, %1, %2" : "=v"(X0) : "v"(st[8*kc2+0]), "v"(st[8*kc2+1]));
            asm("v_cvt_pk_bf16_f32 %0, %1, %2" : "=v"(X1) : "v"(st[8*kc2+2]), "v"(st[8*kc2+3]));
            asm("v_cvt_pk_bf16_f32 %0, %1, %2" : "=v"(Y0) : "v"(st[8*kc2+4]), "v"(st[8*kc2+5]));
            asm("v_cvt_pk_bf16_f32 %0, %1, %2" : "=v"(Y1) : "v"(st[8*kc2+6]), "v"(st[8*kc2+7]));
            asm("v_permlane32_swap_b32 %0, %1" : "+v"(X0), "+v"(Y0));
            asm("v_permlane32_swap_b32 %0, %1" : "+v"(X1), "+v"(Y1));
            union { u32 u[4]; short8 s; } bf;
            bf.u[0] = X0; bf.u[1] = X1; bf.u[2] = Y0; bf.u[3] = Y1;
            // PV for key-chunk kc2 (keys 16*kc2+0..15): col-group 2*kc2+hi
            short8 va0 = *(const short8*)&Vs[p][l31][(2 * kc2 + hi) * 8];
            short8 va1 = *(const short8*)&Vs[p][32 + l31][(2 * kc2 + hi) * 8];
            o0 = mfma32(va0, bf.s, o0);
            o1 = mfma32(va1, bf.s, o1);
        }

        if (more) {
            *(uint4*)&Ks[p ^ 1][srK][scK] = kld;
            *(uint4*)&Vs[p ^ 1][srV][scV] = vld;
        }
        __syncthreads();
        p ^= 1;
    }

    lv += __shfl_xor(lv, 32);
    // bf16 unnormalized partials: Opb[oct*16+bh][q][dh]
    const size_t rowo = ((size_t)(oct * 16 + bh) * N_ + q0 + l31) * DH_;
    #pragma unroll
    for (int go = 0; go < 2; ++go) {
        #pragma unroll
        for (int rq = 0; rq < 4; ++rq) {
            uint2 w;
            if (go == 0) {
                w.x = pkbf(o0[rq*4+0], o0[rq*4+1]);
                w.y = pkbf(o0[rq*4+2], o0[rq*4+3]);
            } else {
                w.x = pkbf(o1[rq*4+0], o1[rq*4+1]);
                w.y = pkbf(o1[rq*4+2], o1[rq*4+3]);
            }
            *(uint2*)(Opb + rowo + go * 32 + 8 * rq + 4 * hi) = w;
        }
    }
    if (hi == 0) lvp[(size_t)(oct * 16 + bh) * N_ + q0 + l31] = lv;
}

// -------- fused combine + out-projection ------------------------------------
// Block = 16 rows x 256 cols. Phase 1: combine 8 bf16 partials + lv sums into
// LDS As[16][264]. Phase 2: 4 waves x (16x64) GEMM, A from LDS. Epilogue:
// out = x + gate*(acc+bias). Grid 512 = 2 blocks/CU.
__global__ __launch_bounds__(256) void gemm_out(
    const u16* __restrict__ Opb, const float* __restrict__ lvp,
    const u16* __restrict__ BT, const float* __restrict__ bias,
    float* __restrict__ out, const float* __restrict__ xin,
    const u16* __restrict__ gate)
{
    __shared__ __align__(16) u16 As[16][264];
    const int tid = threadIdx.x;
    const int m0 = blockIdx.x * 16;

    // ---- phase 1: combine partials -> As
    {
        const int r  = tid >> 4;            // 0..15
        const int kc = (tid & 15) * 16;     // 16-aligned col in [0,256)
        const int t  = m0 + r;
        const int n  = t & 2047, b = t >> 11;
        const int h  = kc >> 6;
        const int bh = b * 4 + h;
        const int dh = kc & 63;
        float a[16];
        #pragma unroll
        for (int i = 0; i < 16; ++i) a[i] = 0.f;
        float lsum = 0.f;
        #pragma unroll
        for (int pp = 0; pp < 8; ++pp) {
            const size_t base = ((size_t)(pp * 16 + bh) * N_ + n) * DH_ + dh;
            const uint4 u0 = *(const uint4*)(Opb + base);
            const uint4 u1 = *(const uint4*)(Opb + base + 8);
            const u32 uu[8] = {u0.x, u0.y, u0.z, u0.w, u1.x, u1.y, u1.z, u1.w};
            #pragma unroll
            for (int i2 = 0; i2 < 8; ++i2) {
                a[i2 * 2]     += b2f((u16)(uu[i2] & 0xffff));
                a[i2 * 2 + 1] += b2f((u16)(uu[i2] >> 16));
            }
            lsum += lvp[(size_t)(pp * 16 + bh) * N_ + n];
        }
        const float rl = 1.0f / lsum;
        uint4 w0, w1;
        w0.x = pkbf(a[0] * rl,  a[1] * rl);  w0.y = pkbf(a[2] * rl,  a[3] * rl);
        w0.z = pkbf(a[4] * rl,  a[5] * rl);  w0.w = pkbf(a[6] * rl,  a[7] * rl);
        w1.x = pkbf(a[8] * rl,  a[9] * rl);  w1.y = pkbf(a[10] * rl, a[11] * rl);
        w1.z = pkbf(a[12] * rl, a[13] * rl); w1.w = pkbf(a[14] * rl, a[15] * rl);
        *(uint4*)&As[r][kc]     = w0;
        *(uint4*)&As[r][kc + 8] = w1;
    }
    __syncthreads();

    // ---- phase 2: GEMM 16 x 64 per wave
    const int wave = tid >> 6, lane = tid & 63;
    const int ln15 = lane & 15, quad = lane >> 4;
    const int n0 = wave * 64;
    const f32x4 zero = {0.f, 0.f, 0.f, 0.f};
    f32x4 acc[4] = {zero, zero, zero, zero};

    #pragma unroll
    for (int k0 = 0; k0 < 256; k0 += 32) {
        const int koff = k0 + quad * 8;
        const short8 a = *(const short8*)&As[ln15][koff];
        #pragma unroll
        for (int j = 0; j < 4; ++j) {
            const short8 bfr = *(const short8*)(BT + (size_t)(n0 + j * 16 + ln15) * 256 + koff);
            acc[j] = mfma16(a, bfr, acc[j]);
        }
    }

    #pragma unroll
    for (int j = 0; j < 4; ++j) {
        const int c = n0 + j * 16 + ln15;
        const float bv = bias[c];
        const int r = quad * 4;
        #pragma unroll
        for (int rg = 0; rg < 4; ++rg) {
            const size_t idx = (size_t)(m0 + r + rg) * 256 + c;
            out[idx] = xin[idx] + b2f(gate[idx]) * (acc[j][rg] + bv);
        }
    }
}

extern "C" void kernel_launch(void* const* d_in, const int* in_sizes, int n_in,
                              void* d_out, int out_size, void* d_ws, size_t ws_size,
                              hipStream_t stream) {
    const float* x      = (const float*)d_in[0];
    const float* freqs  = (const float*)d_in[1];
    const float* g      = (const float*)d_in[2];
    const float* w_qkv  = (const float*)d_in[3];
    const float* b_qkv  = (const float*)d_in[4];
    const float* w_out  = (const float*)d_in[5];
    const float* b_out  = (const float*)d_in[6];
    const float* w_gate = (const float*)d_in[7];
    const float* b_gate = (const float*)d_in[8];
    float* out = (float*)d_out;          // f32 output

    char* ws = (char*)d_ws;
    size_t off = 0;
    auto carve = [&](size_t nelem) -> u16* {
        u16* p = (u16*)(ws + off);
        off += ((nelem * 2 + 255) / 256) * 256;
        return p;
    };
    u16* Qb     = carve((size_t)BN_ * D_);       // [B,H,N,DH]
    u16* Kb     = carve((size_t)BN_ * D_);
    u16* VT     = carve((size_t)BN_ * D_);       // [B,H,DH,N]
    u16* gatb   = carve((size_t)BN_ * D_);
    // wcatT = [wqkvT (768 rows) | wgateT (256 rows)] contiguous, then woutT
    u16* wqkvT  = carve((size_t)768 * 256);
    u16* wgateT = carve((size_t)256 * 256);      // = wqkvT + 768*256
    u16* woutT  = carve((size_t)256 * 256);
    // split-K x8 partials (bf16 O + f32 lv):
    u16*   Opb = carve((size_t)8 * 16 * N_ * DH_);              // 32 MB bf16
    float* lvp = (float*)carve((size_t)8 * 16 * N_ * 2);        // 1 MB f32

    hipLaunchKernelGGL(transw_k, dim3(1024), dim3(256), 0, stream,
                       w_qkv, w_out, w_gate, wqkvT, woutT, wgateT);
    hipLaunchKernelGGL(gemm_front, dim3(64, 8), dim3(256), 0, stream,
                       x, g, wqkvT, b_qkv, b_gate, freqs, Qb, Kb, VT, gatb);
    hipLaunchKernelGGL(attn_k, dim3(2048), dim3(256), 0, stream,
                       Qb, Kb, VT, Opb, lvp);
    hipLaunchKernelGGL(gemm_out, dim3(512), dim3(256), 0, stream,
                       Opb, lvp, woutT, b_out, out, x, gatb);
}

// Round 11
// 148.278 us; speedup vs baseline: 2.4657x; 2.4657x over previous
//
#include <hip/hip_runtime.h>

typedef unsigned short u16;
typedef unsigned int u32;
typedef short short8 __attribute__((ext_vector_type(8)));
typedef float f32x4 __attribute__((ext_vector_type(4)));
typedef float f32x16 __attribute__((ext_vector_type(16)));

#define B_ 4
#define N_ 2048
#define D_ 256
#define H_ 4
#define DH_ 64
#define BN_ 8192

__device__ inline float b2f(u16 u) {
    union { u32 i; float f; } v; v.i = ((u32)u) << 16; return v.f;
}
// round-half-up bf16: 2 VALU ops
__device__ inline u16 f2b(float f) {
    union { float f; u32 i; } v; v.f = f;
    return (u16)((v.i + 0x8000u) >> 16);
}
// pack two f32 -> bf16 pair (lo=a, hi=b) in 3 VALU via v_perm_b32
__device__ inline u32 pkbf(float a, float b) {
    union { float f; u32 i; } ua, ub; ua.f = a; ub.f = b;
    return __builtin_amdgcn_perm(ub.i + 0x8000u, ua.i + 0x8000u, 0x07060302u);
}
__device__ inline f32x4 mfma16(short8 a, short8 b, f32x4 c) {
    return __builtin_amdgcn_mfma_f32_16x16x32_bf16(a, b, c, 0, 0, 0);
}
__device__ inline f32x16 mfma32(short8 a, short8 b, f32x16 c) {
    return __builtin_amdgcn_mfma_f32_32x32x16_bf16(a, b, c, 0, 0, 0);
}

#define QSCALE 0.18033688f   // 0.125 * log2(e)

// -------- weight transpose only (norm lives in gemm_front) ------------------
__global__ __launch_bounds__(256) void transw_k(
    const float* __restrict__ wqkv, const float* __restrict__ wout,
    const float* __restrict__ wgate,
    u16* __restrict__ wqkvT, u16* __restrict__ woutT, u16* __restrict__ wgateT)
{
    int idx = blockIdx.x * 256 + threadIdx.x;   // [0, 262144)
    if (idx < 768 * 256) {
        int nn = idx >> 8, kk = idx & 255;
        wqkvT[idx] = f2b(wqkv[kk * 768 + nn]);
    }
    idx -= 768 * 256;
    if (idx >= 0 && idx < 256 * 256) {
        int nn = idx >> 8, kk = idx & 255;
        woutT[idx]  = f2b(wout[kk * 256 + nn]);
        wgateT[idx] = f2b(wgate[kk * 256 + nn]);
    }
}

// -------- fused norm + front-end GEMM: C = zcrms(x) @ [wqkv | wgate] --------
// Phase 0: each block normalizes its own 128 x-rows into LDS As[128][264]
// (8x redundant across by, L3-absorbed). K-loop reads A from LDS. Epilogue
// column ranges: [0,512) Q,K with in-register RoPE (pair = __shfl_xor(v,1)),
// [512,768) V transposed into VT, [768,1024) sigmoid gate. (Round-10 keep;
// absmax unchanged -> numerically fine.)
__global__ __launch_bounds__(256) void gemm_front(
    const float* __restrict__ x, const float* __restrict__ gw,
    const u16* __restrict__ BT,                 // [1024][256] = [wqkvT|wgateT]
    const float* __restrict__ b_qkv, const float* __restrict__ b_gate,
    const float* __restrict__ freqs,
    u16* __restrict__ Qb, u16* __restrict__ Kb,
    u16* __restrict__ VT, u16* __restrict__ gatb)
{
    __shared__ __align__(16) u16 As[128][264];
    const int tid = threadIdx.x;
    const int wave = tid >> 6, lane = tid & 63;
    const int ln15 = lane & 15, quad = lane >> 4;
    const int by = blockIdx.y;
    const int mb = blockIdx.x * 128;

    // ---- phase 0: zc-RMSNorm rows mb..mb+127 -> As (each wave: 32 rows)
    {
        const float4 gv = *(const float4*)(gw + lane * 4);
        #pragma unroll 4
        for (int rr = 0; rr < 32; ++rr) {
            const int r = wave * 32 + rr;
            const float4 u = *(const float4*)(x + (size_t)(mb + r) * D_ + lane * 4);
            float s  = u.x + u.y + u.z + u.w;
            float s2 = u.x * u.x + u.y * u.y + u.z * u.z + u.w * u.w;
            #pragma unroll
            for (int m = 1; m < 64; m <<= 1) {
                s  += __shfl_xor(s, m);
                s2 += __shfl_xor(s2, m);
            }
            const float mean = s * (1.0f / D_);
            const float var  = s2 * (1.0f / D_) - mean * mean;
            const float rinv = rsqrtf(var + 1e-8f);
            uint2 o;
            o.x = pkbf((u.x - mean) * rinv * gv.x, (u.y - mean) * rinv * gv.y);
            o.y = pkbf((u.z - mean) * rinv * gv.z, (u.w - mean) * rinv * gv.w);
            *(uint2*)&As[r][lane * 4] = o;
        }
    }
    __syncthreads();

    const int ml0 = (wave & 1) * 64;            // m-local base for this wave
    const int m0  = mb + ml0;                   // global m base
    const int n0  = by * 128 + (wave >> 1) * 64;

    const f32x4 zero = {0.f, 0.f, 0.f, 0.f};
    f32x4 acc[4][4];
    #pragma unroll
    for (int i = 0; i < 4; ++i)
        #pragma unroll
        for (int j = 0; j < 4; ++j) acc[i][j] = zero;

    #pragma unroll
    for (int k0 = 0; k0 < 256; k0 += 32) {
        const int koff = k0 + quad * 8;
        short8 a[4], b[4];
        #pragma unroll
        for (int i = 0; i < 4; ++i)
            a[i] = *(const short8*)&As[ml0 + i * 16 + ln15][koff];
        #pragma unroll
        for (int j = 0; j < 4; ++j)
            b[j] = *(const short8*)(BT + (size_t)(n0 + j * 16 + ln15) * 256 + koff);
        #pragma unroll
        for (int i = 0; i < 4; ++i)
            #pragma unroll
            for (int j = 0; j < 4; ++j)
                acc[i][j] = mfma16(a[i], b[j], acc[i][j]);
    }

    if (by < 4) {
        // ---- Q,K + RoPE. c<256 -> Q (scaled); else K. Pair = lane^1.
        #pragma unroll
        for (int j = 0; j < 4; ++j) {
            const int c  = n0 + j * 16 + ln15;
            const int hh = (c >> 6) & 3;
            const int dh = c & 63;
            const int d2 = dh >> 1;
            const bool isQ = (c < 256);
            const bool ev  = ((dh & 1) == 0);
            const float bv = b_qkv[c];
            u16* dst = isQ ? Qb : Kb;
            #pragma unroll
            for (int i = 0; i < 4; ++i) {
                const int r = m0 + i * 16 + quad * 4;
                #pragma unroll
                for (int rg = 0; rg < 4; ++rg) {
                    const int t = r + rg;
                    const int n = t & 2047, b = t >> 11;
                    float v = acc[i][j][rg] + bv;
                    float pv = __shfl_xor(v, 1);
                    const float2 cs = *(const float2*)(freqs + (size_t)n * 64 + d2 * 2);
                    float o = ev ? (v * cs.x - pv * cs.y)
                                 : (pv * cs.y + v * cs.x);
                    if (isQ) o *= QSCALE;
                    dst[((size_t)(b * H_ + hh) * N_ + n) * DH_ + dh] = f2b(o);
                }
            }
        }
    } else if (by < 6) {
        // ---- V, written directly transposed: VT[bh][dh][n] (8B per store)
        #pragma unroll
        for (int j = 0; j < 4; ++j) {
            const int c  = n0 + j * 16 + ln15;      // 512..767
            const int hh = (c >> 6) & 3;
            const int dh = c & 63;
            const float bv = b_qkv[c];
            #pragma unroll
            for (int i = 0; i < 4; ++i) {
                const int r = m0 + i * 16 + quad * 4;  // r%4==0, same b for rg 0..3
                const int n = r & 2047, b = r >> 11;
                uint2 w;
                w.x = pkbf(acc[i][j][0] + bv, acc[i][j][1] + bv);
                w.y = pkbf(acc[i][j][2] + bv, acc[i][j][3] + bv);
                *(uint2*)(VT + ((size_t)(b * H_ + hh) * DH_ + dh) * N_ + n) = w;
            }
        }
    } else {
        // ---- gate: sigmoid -> gatb[t][256]
        #pragma unroll
        for (int j = 0; j < 4; ++j) {
            const int c  = n0 + j * 16 + ln15;      // 768..1023
            const int cg = c - 768;
            const float bv = b_gate[cg];
            #pragma unroll
            for (int i = 0; i < 4; ++i) {
                const int r = m0 + i * 16 + quad * 4;
                #pragma unroll
                for (int rg = 0; rg < 4; ++rg) {
                    float v = acc[i][j][rg] + bv;
                    gatb[(size_t)(r + rg) * 256 + cg] = f2b(1.0f / (1.0f + __expf(-v)));
                }
            }
        }
    }
}

// -------- flash attention, split-K x4, 32x32 MFMA, in-register softmax ------
// REVERTED to round-9 exactly. Round-10 post-mortem: __launch_bounds__(256,8)
// capped VGPR below the ~80-reg live state (o0+o1=32 regs alone) -> total
// scratch spill, 1.15 GB traffic, 250us. 64 VGPR at (256,4) is this body's
// floor; 16 waves/CU stands as the occupancy ceiling for this structure.
__global__ __launch_bounds__(256, 4) void attn_k(
    const u16* __restrict__ Q, const u16* __restrict__ K,
    const u16* __restrict__ VT, u16* __restrict__ Opb,
    float* __restrict__ lvp)
{
    __shared__ __align__(16) u16 Ks[2][64][64];
    __shared__ __align__(16) u16 Vs[2][64][64];
    const int tid = threadIdx.x;
    const int wave = tid >> 6, lane = tid & 63;
    const int l31 = lane & 31, hi = lane >> 5;
    const int id = blockIdx.x;
    // XCD swizzle: id&7 -> fixed bh pair per XCD
    const int bh   = ((id & 7) << 1) | ((id >> 3) & 1);
    const int quar = (id >> 4) & 3;
    const int q0   = (id >> 6) * 128 + wave * 32;
    const int kt0  = quar * 512;

    const u16* Qh = Q + (size_t)bh * N_ * DH_;
    const u16* Kh = K + (size_t)bh * N_ * DH_;
    const u16* Vh = VT + (size_t)bh * DH_ * N_;

    // Q as B-operand: n = q = l31, k = kc*16 + hi*8 + j
    short8 bq[4];
    #pragma unroll
    for (int kc = 0; kc < 4; ++kc)
        bq[kc] = *(const short8*)(Qh + (size_t)(q0 + l31) * DH_ + kc * 16 + hi * 8);

    f32x16 o0, o1;   // O^T[dh 0..31][q], O^T[dh 32..63][q]
    #pragma unroll
    for (int i = 0; i < 16; ++i) { o0[i] = 0.f; o1[i] = 0.f; }
    float lv = 0.f;

    // staging: 256 threads, 2 uint4 K + 2 uint4 V each
    const int srow = tid >> 2, sq4 = tid & 3;
    const int sw = srow & 7;
    const int wg0 = ((sq4) ^ sw) * 8;          // swizzled write cols (u16)
    const int wg1 = ((sq4 + 4) ^ sw) * 8;
    const int rsw = l31 & 7;                   // read-row swizzle phase

    {
        uint4 k0 = *(const uint4*)(Kh + (size_t)(kt0 + srow) * DH_ + sq4 * 8);
        uint4 k1 = *(const uint4*)(Kh + (size_t)(kt0 + srow) * DH_ + (sq4 + 4) * 8);
        uint4 v0 = *(const uint4*)(Vh + (size_t)srow * N_ + kt0 + sq4 * 8);
        uint4 v1 = *(const uint4*)(Vh + (size_t)srow * N_ + kt0 + (sq4 + 4) * 8);
        *(uint4*)&Ks[0][srow][wg0] = k0;
        *(uint4*)&Ks[0][srow][wg1] = k1;
        *(uint4*)&Vs[0][srow][wg0] = v0;
        *(uint4*)&Vs[0][srow][wg1] = v1;
    }
    __syncthreads();

    int p = 0;
    for (int c = 0; c < 8; ++c) {
        const bool more = (c + 1 < 8);
        uint4 k0, k1, v0, v1;
        if (more) {
            const int ktn = kt0 + (c + 1) * 64;
            k0 = *(const uint4*)(Kh + (size_t)(ktn + srow) * DH_ + sq4 * 8);
            k1 = *(const uint4*)(Kh + (size_t)(ktn + srow) * DH_ + (sq4 + 4) * 8);
            v0 = *(const uint4*)(Vh + (size_t)srow * N_ + ktn + sq4 * 8);
            v1 = *(const uint4*)(Vh + (size_t)srow * N_ + ktn + (sq4 + 4) * 8);
        }

        // group-sequential: keys 32g..32g+31 (g = key-row group)
        #pragma unroll
        for (int g = 0; g < 2; ++g) {
            // QK^T: S^T[key][q]; A = K rows (32g + l31), B = Q
            f32x16 st;
            #pragma unroll
            for (int i = 0; i < 16; ++i) st[i] = 0.f;
            #pragma unroll
            for (int kc = 0; kc < 4; ++kc) {
                const int gran = ((2 * kc + hi) ^ rsw) * 8;
                short8 ka = *(const short8*)&Ks[p][g * 32 + l31][gran];
                st = mfma32(ka, bq[kc], st);
            }
            // softmax numerator in place (no running max; QSCALE pre-applied)
            #pragma unroll
            for (int r = 0; r < 16; ++r) {
                st[r] = exp2f(st[r]);
                lv += st[r];
            }
            // pack P into PV B-fragments (T12: cvt_pk + permlane32_swap)
            #pragma unroll
            for (int kc2 = 0; kc2 < 2; ++kc2) {
                u32 X0, X1, Y0, Y1;
                asm("v_cvt_pk_bf16_f32 %0, %1, %2" : "=v"(X0) : "v"(st[8*kc2+0]), "v"(st[8*kc2+1]));
                asm("v_cvt_pk_bf16_f32 %0, %1, %2" : "=v"(X1) : "v"(st[8*kc2+2]), "v"(st[8*kc2+3]));
                asm("v_cvt_pk_bf16_f32 %0, %1, %2" : "=v"(Y0) : "v"(st[8*kc2+4]), "v"(st[8*kc2+5]));
                asm("v_cvt_pk_bf16_f32 %0, %1, %2" : "=v"(Y1) : "v"(st[8*kc2+6]), "v"(st[8*kc2+7]));
                asm("v_permlane32_swap_b32 %0, %1" : "+v"(X0), "+v"(Y0));
                asm("v_permlane32_swap_b32 %0, %1" : "+v"(X1), "+v"(Y1));
                union { u32 u[4]; short8 s; } bf;
                bf.u[0] = X0; bf.u[1] = X1; bf.u[2] = Y0; bf.u[3] = Y1;
                // PV for key-chunk kc = 2g + kc2 (keys 16kc+0..15)
                const int gran = ((2 * (2 * g + kc2) + hi) ^ rsw) * 8;
                short8 va0 = *(const short8*)&Vs[p][l31][gran];
                short8 va1 = *(const short8*)&Vs[p][32 + l31][gran];
                o0 = mfma32(va0, bf.s, o0);
                o1 = mfma32(va1, bf.s, o1);
            }
        }

        if (more) {
            *(uint4*)&Ks[p ^ 1][srow][wg0] = k0;
            *(uint4*)&Ks[p ^ 1][srow][wg1] = k1;
            *(uint4*)&Vs[p ^ 1][srow][wg0] = v0;
            *(uint4*)&Vs[p ^ 1][srow][wg1] = v1;
        }
        __syncthreads();
        p ^= 1;
    }

    lv += __shfl_xor(lv, 32);
    // bf16 unnormalized partials: Opb[quar*16+bh][q][dh]
    const size_t rowo = ((size_t)(quar * 16 + bh) * N_ + q0 + l31) * DH_;
    #pragma unroll
    for (int go = 0; go < 2; ++go) {
        #pragma unroll
        for (int rq = 0; rq < 4; ++rq) {
            uint2 w;
            if (go == 0) {
                w.x = pkbf(o0[rq*4+0], o0[rq*4+1]);
                w.y = pkbf(o0[rq*4+2], o0[rq*4+3]);
            } else {
                w.x = pkbf(o1[rq*4+0], o1[rq*4+1]);
                w.y = pkbf(o1[rq*4+2], o1[rq*4+3]);
            }
            *(uint2*)(Opb + rowo + go * 32 + 8 * rq + 4 * hi) = w;
        }
    }
    if (hi == 0) lvp[(size_t)(quar * 16 + bh) * N_ + q0 + l31] = lv;
}

// -------- fused combine + out-projection ------------------------------------
// Block = 16 rows x 256 cols. Phase 1: combine 4 bf16 partials + lv sums into
// LDS As[16][264]. Phase 2: 4 waves x (16x64) GEMM, A from LDS. Epilogue:
// out = x + gate*(acc+bias). Grid 512 = 2 blocks/CU.
__global__ __launch_bounds__(256) void gemm_out(
    const u16* __restrict__ Opb, const float* __restrict__ lvp,
    const u16* __restrict__ BT, const float* __restrict__ bias,
    float* __restrict__ out, const float* __restrict__ xin,
    const u16* __restrict__ gate)
{
    __shared__ __align__(16) u16 As[16][264];
    const int tid = threadIdx.x;
    const int m0 = blockIdx.x * 16;

    // ---- phase 1: combine partials -> As
    {
        const int r  = tid >> 4;            // 0..15
        const int kc = (tid & 15) * 16;     // 16-aligned col in [0,256)
        const int t  = m0 + r;
        const int n  = t & 2047, b = t >> 11;
        const int h  = kc >> 6;
        const int bh = b * 4 + h;
        const int dh = kc & 63;
        float a[16];
        #pragma unroll
        for (int i = 0; i < 16; ++i) a[i] = 0.f;
        float lsum = 0.f;
        #pragma unroll
        for (int pp = 0; pp < 4; ++pp) {
            const size_t base = ((size_t)(pp * 16 + bh) * N_ + n) * DH_ + dh;
            const uint4 u0 = *(const uint4*)(Opb + base);
            const uint4 u1 = *(const uint4*)(Opb + base + 8);
            const u32 uu[8] = {u0.x, u0.y, u0.z, u0.w, u1.x, u1.y, u1.z, u1.w};
            #pragma unroll
            for (int i2 = 0; i2 < 8; ++i2) {
                a[i2 * 2]     += b2f((u16)(uu[i2] & 0xffff));
                a[i2 * 2 + 1] += b2f((u16)(uu[i2] >> 16));
            }
            lsum += lvp[(size_t)(pp * 16 + bh) * N_ + n];
        }
        const float rl = 1.0f / lsum;
        uint4 w0, w1;
        w0.x = pkbf(a[0] * rl,  a[1] * rl);  w0.y = pkbf(a[2] * rl,  a[3] * rl);
        w0.z = pkbf(a[4] * rl,  a[5] * rl);  w0.w = pkbf(a[6] * rl,  a[7] * rl);
        w1.x = pkbf(a[8] * rl,  a[9] * rl);  w1.y = pkbf(a[10] * rl, a[11] * rl);
        w1.z = pkbf(a[12] * rl, a[13] * rl); w1.w = pkbf(a[14] * rl, a[15] * rl);
        *(uint4*)&As[r][kc]     = w0;
        *(uint4*)&As[r][kc + 8] = w1;
    }
    __syncthreads();

    // ---- phase 2: GEMM 16 x 64 per wave
    const int wave = tid >> 6, lane = tid & 63;
    const int ln15 = lane & 15, quad = lane >> 4;
    const int n0 = wave * 64;
    const f32x4 zero = {0.f, 0.f, 0.f, 0.f};
    f32x4 acc[4] = {zero, zero, zero, zero};

    #pragma unroll
    for (int k0 = 0; k0 < 256; k0 += 32) {
        const int koff = k0 + quad * 8;
        const short8 a = *(const short8*)&As[ln15][koff];
        #pragma unroll
        for (int j = 0; j < 4; ++j) {
            const short8 bfr = *(const short8*)(BT + (size_t)(n0 + j * 16 + ln15) * 256 + koff);
            acc[j] = mfma16(a, bfr, acc[j]);
        }
    }

    #pragma unroll
    for (int j = 0; j < 4; ++j) {
        const int c = n0 + j * 16 + ln15;
        const float bv = bias[c];
        const int r = quad * 4;
        #pragma unroll
        for (int rg = 0; rg < 4; ++rg) {
            const size_t idx = (size_t)(m0 + r + rg) * 256 + c;
            out[idx] = xin[idx] + b2f(gate[idx]) * (acc[j][rg] + bv);
        }
    }
}

extern "C" void kernel_launch(void* const* d_in, const int* in_sizes, int n_in,
                              void* d_out, int out_size, void* d_ws, size_t ws_size,
                              hipStream_t stream) {
    const float* x      = (const float*)d_in[0];
    const float* freqs  = (const float*)d_in[1];
    const float* g      = (const float*)d_in[2];
    const float* w_qkv  = (const float*)d_in[3];
    const float* b_qkv  = (const float*)d_in[4];
    const float* w_out  = (const float*)d_in[5];
    const float* b_out  = (const float*)d_in[6];
    const float* w_gate = (const float*)d_in[7];
    const float* b_gate = (const float*)d_in[8];
    float* out = (float*)d_out;          // f32 output

    char* ws = (char*)d_ws;
    size_t off = 0;
    auto carve = [&](size_t nelem) -> u16* {
        u16* p = (u16*)(ws + off);
        off += ((nelem * 2 + 255) / 256) * 256;
        return p;
    };
    u16* Qb     = carve((size_t)BN_ * D_);       // [B,H,N,DH]
    u16* Kb     = carve((size_t)BN_ * D_);
    u16* VT     = carve((size_t)BN_ * D_);       // [B,H,DH,N]
    u16* gatb   = carve((size_t)BN_ * D_);
    // wcatT = [wqkvT (768 rows) | wgateT (256 rows)] contiguous, then woutT
    u16* wqkvT  = carve((size_t)768 * 256);
    u16* wgateT = carve((size_t)256 * 256);      // = wqkvT + 768*256
    u16* woutT  = carve((size_t)256 * 256);
    // split-K x4 partials (bf16 O + f32 lv):
    u16*   Opb = carve((size_t)4 * 16 * N_ * DH_);              // 16 MB bf16
    float* lvp = (float*)carve((size_t)4 * 16 * N_ * 2);        // 512 KB f32

    hipLaunchKernelGGL(transw_k, dim3(1024), dim3(256), 0, stream,
                       w_qkv, w_out, w_gate, wqkvT, woutT, wgateT);
    hipLaunchKernelGGL(gemm_front, dim3(64, 8), dim3(256), 0, stream,
                       x, g, wqkvT, b_qkv, b_gate, freqs, Qb, Kb, VT, gatb);
    hipLaunchKernelGGL(attn_k, dim3(1024), dim3(256), 0, stream,
                       Qb, Kb, VT, Opb, lvp);
    hipLaunchKernelGGL(gemm_out, dim3(512), dim3(256), 0, stream,
                       Opb, lvp, woutT, b_out, out, x, gatb);
}

// Round 12
// 148.008 us; speedup vs baseline: 2.4702x; 1.0018x over previous
//
#include <hip/hip_runtime.h>

typedef unsigned short u16;
typedef unsigned int u32;
typedef short short8 __attribute__((ext_vector_type(8)));
typedef float f32x4 __attribute__((ext_vector_type(4)));
typedef float f32x16 __attribute__((ext_vector_type(16)));

#define B_ 4
#define N_ 2048
#define D_ 256
#define H_ 4
#define DH_ 64
#define BN_ 8192

__device__ inline float b2f(u16 u) {
    union { u32 i; float f; } v; v.i = ((u32)u) << 16; return v.f;
}
// round-half-up bf16: 2 VALU ops
__device__ inline u16 f2b(float f) {
    union { float f; u32 i; } v; v.f = f;
    return (u16)((v.i + 0x8000u) >> 16);
}
// pack two f32 -> bf16 pair (lo=a, hi=b) in 3 VALU via v_perm_b32
__device__ inline u32 pkbf(float a, float b) {
    union { float f; u32 i; } ua, ub; ua.f = a; ub.f = b;
    return __builtin_amdgcn_perm(ub.i + 0x8000u, ua.i + 0x8000u, 0x07060302u);
}
__device__ inline f32x4 mfma16(short8 a, short8 b, f32x4 c) {
    return __builtin_amdgcn_mfma_f32_16x16x32_bf16(a, b, c, 0, 0, 0);
}
__device__ inline f32x16 mfma32(short8 a, short8 b, f32x16 c) {
    return __builtin_amdgcn_mfma_f32_32x32x16_bf16(a, b, c, 0, 0, 0);
}

#define QSCALE 0.18033688f   // 0.125 * log2(e)

// -------- weight transpose only (norm lives in gemm_front) ------------------
__global__ __launch_bounds__(256) void transw_k(
    const float* __restrict__ wqkv, const float* __restrict__ wout,
    const float* __restrict__ wgate,
    u16* __restrict__ wqkvT, u16* __restrict__ woutT, u16* __restrict__ wgateT)
{
    int idx = blockIdx.x * 256 + threadIdx.x;   // [0, 262144)
    if (idx < 768 * 256) {
        int nn = idx >> 8, kk = idx & 255;
        wqkvT[idx] = f2b(wqkv[kk * 768 + nn]);
    }
    idx -= 768 * 256;
    if (idx >= 0 && idx < 256 * 256) {
        int nn = idx >> 8, kk = idx & 255;
        woutT[idx]  = f2b(wout[kk * 256 + nn]);
        wgateT[idx] = f2b(wgate[kk * 256 + nn]);
    }
}

// -------- fused norm + front-end GEMM: C = zcrms(x) @ [wqkv | wgate] --------
// Phase 0: block-local zc-RMSNorm of 128 x-rows -> As. K-loop reads A from
// LDS. Round-12: epilogue STORE-COALESCING — the old epilogue issued 2-8B
// scattered stores (Q/K: 64 scalar u16/thread, V: 8B at 4KB row stride) =
// suspected hidden cost of this kernel. Now: after the k-loop, reuse the
// dead As buffer as per-wave staging (64x72 u16 each); stage the tile in
// output orientation (Q/K/gate [t][dh]; V transposed [dh][n]), per-wave
// lgkmcnt wait (no barrier), then uniform drain: 8 x uint4/lane, lanes
// tiled 8 rows x 8 chunks -> dense 1KB per store instruction. Q/K panels
// become fully contiguous 8KB/wave; V rows full 128B runs. Math unchanged.
__global__ __launch_bounds__(256) void gemm_front(
    const float* __restrict__ x, const float* __restrict__ gw,
    const u16* __restrict__ BT,                 // [1024][256] = [wqkvT|wgateT]
    const float* __restrict__ b_qkv, const float* __restrict__ b_gate,
    const float* __restrict__ freqs,
    u16* __restrict__ Qb, u16* __restrict__ Kb,
    u16* __restrict__ VT, u16* __restrict__ gatb)
{
    __shared__ __align__(16) u16 As[128][264];
    const int tid = threadIdx.x;
    const int wave = tid >> 6, lane = tid & 63;
    const int ln15 = lane & 15, quad = lane >> 4;
    const int by = blockIdx.y;
    const int mb = blockIdx.x * 128;

    // ---- phase 0: zc-RMSNorm rows mb..mb+127 -> As (each wave: 32 rows)
    {
        const float4 gv = *(const float4*)(gw + lane * 4);
        #pragma unroll 4
        for (int rr = 0; rr < 32; ++rr) {
            const int r = wave * 32 + rr;
            const float4 u = *(const float4*)(x + (size_t)(mb + r) * D_ + lane * 4);
            float s  = u.x + u.y + u.z + u.w;
            float s2 = u.x * u.x + u.y * u.y + u.z * u.z + u.w * u.w;
            #pragma unroll
            for (int m = 1; m < 64; m <<= 1) {
                s  += __shfl_xor(s, m);
                s2 += __shfl_xor(s2, m);
            }
            const float mean = s * (1.0f / D_);
            const float var  = s2 * (1.0f / D_) - mean * mean;
            const float rinv = rsqrtf(var + 1e-8f);
            uint2 o;
            o.x = pkbf((u.x - mean) * rinv * gv.x, (u.y - mean) * rinv * gv.y);
            o.y = pkbf((u.z - mean) * rinv * gv.z, (u.w - mean) * rinv * gv.w);
            *(uint2*)&As[r][lane * 4] = o;
        }
    }
    __syncthreads();

    const int ml0 = (wave & 1) * 64;            // m-local base for this wave
    const int m0  = mb + ml0;                   // global m base
    const int n0  = by * 128 + (wave >> 1) * 64;

    const f32x4 zero = {0.f, 0.f, 0.f, 0.f};
    f32x4 acc[4][4];
    #pragma unroll
    for (int i = 0; i < 4; ++i)
        #pragma unroll
        for (int j = 0; j < 4; ++j) acc[i][j] = zero;

    #pragma unroll
    for (int k0 = 0; k0 < 256; k0 += 32) {
        const int koff = k0 + quad * 8;
        short8 a[4], b[4];
        #pragma unroll
        for (int i = 0; i < 4; ++i)
            a[i] = *(const short8*)&As[ml0 + i * 16 + ln15][koff];
        #pragma unroll
        for (int j = 0; j < 4; ++j)
            b[j] = *(const short8*)(BT + (size_t)(n0 + j * 16 + ln15) * 256 + koff);
        #pragma unroll
        for (int i = 0; i < 4; ++i)
            #pragma unroll
            for (int j = 0; j < 4; ++j)
                acc[i][j] = mfma16(a[i], b[j], acc[i][j]);
    }

    // ---- epilogue: all waves done reading As -> reuse it as store staging
    __syncthreads();
    u16* E = ((u16*)As) + wave * (64 * 72);     // per-wave 64x72 u16

    const int b  = m0 >> 11;                    // batch of this 64-row panel
    const int nb = m0 & 2047;                   // n base

    if (by < 4) {
        // ---- Q,K + RoPE (pair = lane^1). One head panel per wave.
        const int hh  = (n0 >> 6) & 3;
        const bool isQ = (n0 < 256);
        #pragma unroll
        for (int j = 0; j < 4; ++j) {
            const int dh = j * 16 + ln15;
            const int d2 = dh >> 1;
            const bool ev = ((dh & 1) == 0);
            const float bv = b_qkv[n0 + dh];
            #pragma unroll
            for (int i = 0; i < 4; ++i) {
                const int rl = i * 16 + quad * 4;
                #pragma unroll
                for (int rg = 0; rg < 4; ++rg) {
                    const int n = nb + rl + rg;
                    float v = acc[i][j][rg] + bv;
                    float pv = __shfl_xor(v, 1);
                    const float2 cs = *(const float2*)(freqs + (size_t)n * 64 + d2 * 2);
                    float o = ev ? (v * cs.x - pv * cs.y)
                                 : (pv * cs.y + v * cs.x);
                    if (isQ) o *= QSCALE;
                    E[(rl + rg) * 72 + dh] = f2b(o);
                }
            }
        }
        asm volatile("s_waitcnt lgkmcnt(0)" ::: "memory");
        u16* dst0 = (isQ ? Qb : Kb) + ((size_t)(b * H_ + hh) * N_ + nb) * DH_;
        #pragma unroll
        for (int s = 0; s < 8; ++s) {
            const int row = s * 8 + (lane >> 3);
            const int ch  = (lane & 7) * 8;
            uint4 vv = *(const uint4*)&E[row * 72 + ch];
            *(uint4*)(dst0 + (size_t)row * DH_ + ch) = vv;   // contiguous 8KB/wave
        }
    } else if (by < 6) {
        // ---- V, staged transposed [dh][n] -> 128B runs per VT row
        const int hh = ((n0 - 512) >> 6) & 3;
        #pragma unroll
        for (int j = 0; j < 4; ++j) {
            const int dh = j * 16 + ln15;
            const float bv = b_qkv[n0 + dh];
            #pragma unroll
            for (int i = 0; i < 4; ++i) {
                const int rl = i * 16 + quad * 4;
                uint2 w;
                w.x = pkbf(acc[i][j][0] + bv, acc[i][j][1] + bv);
                w.y = pkbf(acc[i][j][2] + bv, acc[i][j][3] + bv);
                *(uint2*)&E[dh * 72 + rl] = w;
            }
        }
        asm volatile("s_waitcnt lgkmcnt(0)" ::: "memory");
        u16* dst0 = VT + (size_t)(b * H_ + hh) * DH_ * N_ + nb;
        #pragma unroll
        for (int s = 0; s < 8; ++s) {
            const int row = s * 8 + (lane >> 3);   // dh
            const int ch  = (lane & 7) * 8;        // n offset
            uint4 vv = *(const uint4*)&E[row * 72 + ch];
            *(uint4*)(dst0 + (size_t)row * N_ + ch) = vv;    // 128B runs
        }
    } else {
        // ---- gate: sigmoid -> gatb[t][256], 128B runs
        const int cg0 = n0 - 768;
        #pragma unroll
        for (int j = 0; j < 4; ++j) {
            const int cl = j * 16 + ln15;
            const float bv = b_gate[cg0 + cl];
            #pragma unroll
            for (int i = 0; i < 4; ++i) {
                const int rl = i * 16 + quad * 4;
                #pragma unroll
                for (int rg = 0; rg < 4; ++rg) {
                    float v = acc[i][j][rg] + bv;
                    E[(rl + rg) * 72 + cl] = f2b(1.0f / (1.0f + __expf(-v)));
                }
            }
        }
        asm volatile("s_waitcnt lgkmcnt(0)" ::: "memory");
        u16* dst0 = gatb + (size_t)m0 * 256 + cg0;
        #pragma unroll
        for (int s = 0; s < 8; ++s) {
            const int row = s * 8 + (lane >> 3);
            const int ch  = (lane & 7) * 8;
            uint4 vv = *(const uint4*)&E[row * 72 + ch];
            *(uint4*)(dst0 + (size_t)row * 256 + ch) = vv;
        }
    }
}

// -------- flash attention, split-K x4, 32x32 MFMA, in-register softmax ------
// (R9 version; R10's (256,8) VGPR cap caused total scratch spill — 64 VGPR
// at (256,4) is this body's floor; 16 waves/CU is the occupancy ceiling.)
__global__ __launch_bounds__(256, 4) void attn_k(
    const u16* __restrict__ Q, const u16* __restrict__ K,
    const u16* __restrict__ VT, u16* __restrict__ Opb,
    float* __restrict__ lvp)
{
    __shared__ __align__(16) u16 Ks[2][64][64];
    __shared__ __align__(16) u16 Vs[2][64][64];
    const int tid = threadIdx.x;
    const int wave = tid >> 6, lane = tid & 63;
    const int l31 = lane & 31, hi = lane >> 5;
    const int id = blockIdx.x;
    // XCD swizzle: id&7 -> fixed bh pair per XCD
    const int bh   = ((id & 7) << 1) | ((id >> 3) & 1);
    const int quar = (id >> 4) & 3;
    const int q0   = (id >> 6) * 128 + wave * 32;
    const int kt0  = quar * 512;

    const u16* Qh = Q + (size_t)bh * N_ * DH_;
    const u16* Kh = K + (size_t)bh * N_ * DH_;
    const u16* Vh = VT + (size_t)bh * DH_ * N_;

    // Q as B-operand: n = q = l31, k = kc*16 + hi*8 + j
    short8 bq[4];
    #pragma unroll
    for (int kc = 0; kc < 4; ++kc)
        bq[kc] = *(const short8*)(Qh + (size_t)(q0 + l31) * DH_ + kc * 16 + hi * 8);

    f32x16 o0, o1;   // O^T[dh 0..31][q], O^T[dh 32..63][q]
    #pragma unroll
    for (int i = 0; i < 16; ++i) { o0[i] = 0.f; o1[i] = 0.f; }
    float lv = 0.f;

    // staging: 256 threads, 2 uint4 K + 2 uint4 V each
    const int srow = tid >> 2, sq4 = tid & 3;
    const int sw = srow & 7;
    const int wg0 = ((sq4) ^ sw) * 8;          // swizzled write cols (u16)
    const int wg1 = ((sq4 + 4) ^ sw) * 8;
    const int rsw = l31 & 7;                   // read-row swizzle phase

    {
        uint4 k0 = *(const uint4*)(Kh + (size_t)(kt0 + srow) * DH_ + sq4 * 8);
        uint4 k1 = *(const uint4*)(Kh + (size_t)(kt0 + srow) * DH_ + (sq4 + 4) * 8);
        uint4 v0 = *(const uint4*)(Vh + (size_t)srow * N_ + kt0 + sq4 * 8);
        uint4 v1 = *(const uint4*)(Vh + (size_t)srow * N_ + kt0 + (sq4 + 4) * 8);
        *(uint4*)&Ks[0][srow][wg0] = k0;
        *(uint4*)&Ks[0][srow][wg1] = k1;
        *(uint4*)&Vs[0][srow][wg0] = v0;
        *(uint4*)&Vs[0][srow][wg1] = v1;
    }
    __syncthreads();

    int p = 0;
    for (int c = 0; c < 8; ++c) {
        const bool more = (c + 1 < 8);
        uint4 k0, k1, v0, v1;
        if (more) {
            const int ktn = kt0 + (c + 1) * 64;
            k0 = *(const uint4*)(Kh + (size_t)(ktn + srow) * DH_ + sq4 * 8);
            k1 = *(const uint4*)(Kh + (size_t)(ktn + srow) * DH_ + (sq4 + 4) * 8);
            v0 = *(const uint4*)(Vh + (size_t)srow * N_ + ktn + sq4 * 8);
            v1 = *(const uint4*)(Vh + (size_t)srow * N_ + ktn + (sq4 + 4) * 8);
        }

        // group-sequential: keys 32g..32g+31 (g = key-row group)
        #pragma unroll
        for (int g = 0; g < 2; ++g) {
            // QK^T: S^T[key][q]; A = K rows (32g + l31), B = Q
            f32x16 st;
            #pragma unroll
            for (int i = 0; i < 16; ++i) st[i] = 0.f;
            #pragma unroll
            for (int kc = 0; kc < 4; ++kc) {
                const int gran = ((2 * kc + hi) ^ rsw) * 8;
                short8 ka = *(const short8*)&Ks[p][g * 32 + l31][gran];
                st = mfma32(ka, bq[kc], st);
            }
            // softmax numerator in place (no running max; QSCALE pre-applied)
            #pragma unroll
            for (int r = 0; r < 16; ++r) {
                st[r] = exp2f(st[r]);
                lv += st[r];
            }
            // pack P into PV B-fragments (T12: cvt_pk + permlane32_swap)
            #pragma unroll
            for (int kc2 = 0; kc2 < 2; ++kc2) {
                u32 X0, X1, Y0, Y1;
                asm("v_cvt_pk_bf16_f32 %0, %1, %2" : "=v"(X0) : "v"(st[8*kc2+0]), "v"(st[8*kc2+1]));
                asm("v_cvt_pk_bf16_f32 %0, %1, %2" : "=v"(X1) : "v"(st[8*kc2+2]), "v"(st[8*kc2+3]));
                asm("v_cvt_pk_bf16_f32 %0, %1, %2" : "=v"(Y0) : "v"(st[8*kc2+4]), "v"(st[8*kc2+5]));
                asm("v_cvt_pk_bf16_f32 %0, %1, %2" : "=v"(Y1) : "v"(st[8*kc2+6]), "v"(st[8*kc2+7]));
                asm("v_permlane32_swap_b32 %0, %1" : "+v"(X0), "+v"(Y0));
                asm("v_permlane32_swap_b32 %0, %1" : "+v"(X1), "+v"(Y1));
                union { u32 u[4]; short8 s; } bf;
                bf.u[0] = X0; bf.u[1] = X1; bf.u[2] = Y0; bf.u[3] = Y1;
                // PV for key-chunk kc = 2g + kc2 (keys 16kc+0..15)
                const int gran = ((2 * (2 * g + kc2) + hi) ^ rsw) * 8;
                short8 va0 = *(const short8*)&Vs[p][l31][gran];
                short8 va1 = *(const short8*)&Vs[p][32 + l31][gran];
                o0 = mfma32(va0, bf.s, o0);
                o1 = mfma32(va1, bf.s, o1);
            }
        }

        if (more) {
            *(uint4*)&Ks[p ^ 1][srow][wg0] = k0;
            *(uint4*)&Ks[p ^ 1][srow][wg1] = k1;
            *(uint4*)&Vs[p ^ 1][srow][wg0] = v0;
            *(uint4*)&Vs[p ^ 1][srow][wg1] = v1;
        }
        __syncthreads();
        p ^= 1;
    }

    lv += __shfl_xor(lv, 32);
    // bf16 unnormalized partials: Opb[quar*16+bh][q][dh]
    const size_t rowo = ((size_t)(quar * 16 + bh) * N_ + q0 + l31) * DH_;
    #pragma unroll
    for (int go = 0; go < 2; ++go) {
        #pragma unroll
        for (int rq = 0; rq < 4; ++rq) {
            uint2 w;
            if (go == 0) {
                w.x = pkbf(o0[rq*4+0], o0[rq*4+1]);
                w.y = pkbf(o0[rq*4+2], o0[rq*4+3]);
            } else {
                w.x = pkbf(o1[rq*4+0], o1[rq*4+1]);
                w.y = pkbf(o1[rq*4+2], o1[rq*4+3]);
            }
            *(uint2*)(Opb + rowo + go * 32 + 8 * rq + 4 * hi) = w;
        }
    }
    if (hi == 0) lvp[(size_t)(quar * 16 + bh) * N_ + q0 + l31] = lv;
}

// -------- fused combine + out-projection ------------------------------------
// Block = 16 rows x 256 cols. Phase 1: combine 4 bf16 partials + lv sums into
// LDS As[16][264]. Phase 2: 4 waves x (16x64) GEMM, A from LDS. Epilogue:
// out = x + gate*(acc+bias). Grid 512 = 2 blocks/CU.
__global__ __launch_bounds__(256) void gemm_out(
    const u16* __restrict__ Opb, const float* __restrict__ lvp,
    const u16* __restrict__ BT, const float* __restrict__ bias,
    float* __restrict__ out, const float* __restrict__ xin,
    const u16* __restrict__ gate)
{
    __shared__ __align__(16) u16 As[16][264];
    const int tid = threadIdx.x;
    const int m0 = blockIdx.x * 16;

    // ---- phase 1: combine partials -> As
    {
        const int r  = tid >> 4;            // 0..15
        const int kc = (tid & 15) * 16;     // 16-aligned col in [0,256)
        const int t  = m0 + r;
        const int n  = t & 2047, b = t >> 11;
        const int h  = kc >> 6;
        const int bh = b * 4 + h;
        const int dh = kc & 63;
        float a[16];
        #pragma unroll
        for (int i = 0; i < 16; ++i) a[i] = 0.f;
        float lsum = 0.f;
        #pragma unroll
        for (int pp = 0; pp < 4; ++pp) {
            const size_t base = ((size_t)(pp * 16 + bh) * N_ + n) * DH_ + dh;
            const uint4 u0 = *(const uint4*)(Opb + base);
            const uint4 u1 = *(const uint4*)(Opb + base + 8);
            const u32 uu[8] = {u0.x, u0.y, u0.z, u0.w, u1.x, u1.y, u1.z, u1.w};
            #pragma unroll
            for (int i2 = 0; i2 < 8; ++i2) {
                a[i2 * 2]     += b2f((u16)(uu[i2] & 0xffff));
                a[i2 * 2 + 1] += b2f((u16)(uu[i2] >> 16));
            }
            lsum += lvp[(size_t)(pp * 16 + bh) * N_ + n];
        }
        const float rl = 1.0f / lsum;
        uint4 w0, w1;
        w0.x = pkbf(a[0] * rl,  a[1] * rl);  w0.y = pkbf(a[2] * rl,  a[3] * rl);
        w0.z = pkbf(a[4] * rl,  a[5] * rl);  w0.w = pkbf(a[6] * rl,  a[7] * rl);
        w1.x = pkbf(a[8] * rl,  a[9] * rl);  w1.y = pkbf(a[10] * rl, a[11] * rl);
        w1.z = pkbf(a[12] * rl, a[13] * rl); w1.w = pkbf(a[14] * rl, a[15] * rl);
        *(uint4*)&As[r][kc]     = w0;
        *(uint4*)&As[r][kc + 8] = w1;
    }
    __syncthreads();

    // ---- phase 2: GEMM 16 x 64 per wave
    const int wave = tid >> 6, lane = tid & 63;
    const int ln15 = lane & 15, quad = lane >> 4;
    const int n0 = wave * 64;
    const f32x4 zero = {0.f, 0.f, 0.f, 0.f};
    f32x4 acc[4] = {zero, zero, zero, zero};

    #pragma unroll
    for (int k0 = 0; k0 < 256; k0 += 32) {
        const int koff = k0 + quad * 8;
        const short8 a = *(const short8*)&As[ln15][koff];
        #pragma unroll
        for (int j = 0; j < 4; ++j) {
            const short8 bfr = *(const short8*)(BT + (size_t)(n0 + j * 16 + ln15) * 256 + koff);
            acc[j] = mfma16(a, bfr, acc[j]);
        }
    }

    #pragma unroll
    for (int j = 0; j < 4; ++j) {
        const int c = n0 + j * 16 + ln15;
        const float bv = bias[c];
        const int r = quad * 4;
        #pragma unroll
        for (int rg = 0; rg < 4; ++rg) {
            const size_t idx = (size_t)(m0 + r + rg) * 256 + c;
            out[idx] = xin[idx] + b2f(gate[idx]) * (acc[j][rg] + bv);
        }
    }
}

extern "C" void kernel_launch(void* const* d_in, const int* in_sizes, int n_in,
                              void* d_out, int out_size, void* d_ws, size_t ws_size,
                              hipStream_t stream) {
    const float* x      = (const float*)d_in[0];
    const float* freqs  = (const float*)d_in[1];
    const float* g      = (const float*)d_in[2];
    const float* w_qkv  = (const float*)d_in[3];
    const float* b_qkv  = (const float*)d_in[4];
    const float* w_out  = (const float*)d_in[5];
    const float* b_out  = (const float*)d_in[6];
    const float* w_gate = (const float*)d_in[7];
    const float* b_gate = (const float*)d_in[8];
    float* out = (float*)d_out;          // f32 output

    char* ws = (char*)d_ws;
    size_t off = 0;
    auto carve = [&](size_t nelem) -> u16* {
        u16* p = (u16*)(ws + off);
        off += ((nelem * 2 + 255) / 256) * 256;
        return p;
    };
    u16* Qb     = carve((size_t)BN_ * D_);       // [B,H,N,DH]
    u16* Kb     = carve((size_t)BN_ * D_);
    u16* VT     = carve((size_t)BN_ * D_);       // [B,H,DH,N]
    u16* gatb   = carve((size_t)BN_ * D_);
    // wcatT = [wqkvT (768 rows) | wgateT (256 rows)] contiguous, then woutT
    u16* wqkvT  = carve((size_t)768 * 256);
    u16* wgateT = carve((size_t)256 * 256);      // = wqkvT + 768*256
    u16* woutT  = carve((size_t)256 * 256);
    // split-K x4 partials (bf16 O + f32 lv):
    u16*   Opb = carve((size_t)4 * 16 * N_ * DH_);              // 16 MB bf16
    float* lvp = (float*)carve((size_t)4 * 16 * N_ * 2);        // 512 KB f32

    hipLaunchKernelGGL(transw_k, dim3(1024), dim3(256), 0, stream,
                       w_qkv, w_out, w_gate, wqkvT, woutT, wgateT);
    hipLaunchKernelGGL(gemm_front, dim3(64, 8), dim3(256), 0, stream,
                       x, g, wqkvT, b_qkv, b_gate, freqs, Qb, Kb, VT, gatb);
    hipLaunchKernelGGL(attn_k, dim3(1024), dim3(256), 0, stream,
                       Qb, Kb, VT, Opb, lvp);
    hipLaunchKernelGGL(gemm_out, dim3(512), dim3(256), 0, stream,
                       Opb, lvp, woutT, b_out, out, x, gatb);
}